// Round 12
// baseline (342.814 us; speedup 1.0000x reference)
//
#include <hip/hip_runtime.h>

#define WIN     12
#define GROUP   128
#define NBATCH  4
#define MAXN    87              // ceil(1024/12)+1 = max_nx = max_ny
#define MWP     (MAXN*MAXN)     // 7569 windows per batch
#define NW      (NBATCH*MWP)    // 30276 batch-major window bins
#define NWORDS  5               // ceil(144/32) bitmap words per window
#define CH      128             // feature channels
#define BMWORDS (NW*NWORDS)     // 151380
#define SCANBLK 30              // ceil(NW/1024) scan blocks per axis

typedef float f32x4 __attribute__((ext_vector_type(4)));

// scratch layout (u32 units) at S = (unsigned*)(out + padBase):
#define OFF_BMY   BMWORDS
#define OFF_WLOCX (2*BMWORDS)
#define OFF_WLOCY (2*BMWORDS + NW)
#define OFF_BSUM  (2*BMWORDS + 2*NW)
#define OFF_BOFF  (2*BMWORDS + 2*NW + 2*SCANBLK)

// one pass over coords: set occupancy bits in BOTH axis bitmaps
__global__ void k_bits_both(const int* __restrict__ coords, int n, unsigned* __restrict__ S) {
    int i = blockIdx.x * blockDim.x + threadIdx.x;
    if (i >= n) return;
    int b = coords[3 * i];
    int y = coords[3 * i + 1];
    int x = coords[3 * i + 2];
    if (b < 0 || b >= NBATCH || x < 0 || y < 0) return;
    int wx = x / WIN, cx = x % WIN;
    int wy = y / WIN, cy = y % WIN;
    int binx = b * MWP + wx * MAXN + wy, kx = cx * WIN + cy;
    int biny = b * MWP + wy * MAXN + wx, ky = cy * WIN + cx;
    atomicOr(&S[binx * NWORDS + (kx >> 5)], 1u << (kx & 31));
    atomicOr(&S[OFF_BMY + biny * NWORDS + (ky >> 5)], 1u << (ky & 31));
}

// per-1024-bin local exclusive scan + block totals. blockIdx < SCANBLK -> X axis.
__global__ void k_scan_local(unsigned* __restrict__ S) {
    int axis = blockIdx.x >= SCANBLK;
    int blk = blockIdx.x - axis * SCANBLK;
    const unsigned* bm = S + (axis ? OFF_BMY : 0);
    unsigned* wloc = S + (axis ? OFF_WLOCY : OFF_WLOCX);
    __shared__ unsigned sdata[1024];
    int t = threadIdx.x;
    int w = blk * 1024 + t;
    unsigned cnt = 0;
    if (w < NW) {
#pragma unroll
        for (int k = 0; k < NWORDS; ++k) cnt += __popc(bm[w * NWORDS + k]);
    }
    sdata[t] = cnt;
    __syncthreads();
    for (int off = 1; off < 1024; off <<= 1) {
        unsigned v = (t >= off) ? sdata[t - off] : 0u;
        __syncthreads();
        sdata[t] += v;
        __syncthreads();
    }
    if (w < NW) wloc[w] = sdata[t] - cnt;
    if (t == 1023) S[OFF_BSUM + blockIdx.x] = sdata[1023];
}

// scan the 2x30 block totals (trivial serial per axis)
__global__ void k_scan_top(unsigned* __restrict__ S) {
    int t = threadIdx.x;
    if (t < 2) {
        unsigned acc = 0;
        for (int k = 0; k < SCANBLK; ++k) {
            S[OFF_BOFF + t * SCANBLK + k] = acc;
            acc += S[OFF_BSUM + t * SCANBLK + k];
        }
    }
}

__device__ __forceinline__ unsigned rank_in(const unsigned* __restrict__ bm, int bin, int k) {
    int wi = k >> 5;
    unsigned bit = (unsigned)(k & 31);
    unsigned r = 0;
    const unsigned* wp = &bm[bin * NWORDS];
#pragma unroll
    for (int w = 0; w < NWORDS; ++w) {
        unsigned m = wp[w];
        if (w < wi) r += __popc(m);
        else if (w == wi) r += __popc(m & ((1u << bit) - 1u));
    }
    return r;
}

// per point: perm_x, perm_y (scattered 4B) + win2flat (sequential)
__global__ void k_finalize(const int* __restrict__ coords, int n,
                           const unsigned* __restrict__ S,
                           float* __restrict__ out, int nper, int gap, long P) {
    int i = blockIdx.x * blockDim.x + threadIdx.x;
    if (i >= n) return;
    int b = coords[3 * i];
    int y = coords[3 * i + 1];
    int x = coords[3 * i + 2];
    if (b < 0 || b >= NBATCH || x < 0 || y < 0) return;
    int wx = x / WIN, cx = x % WIN;
    int wy = y / WIN, cy = y % WIN;

    int binx = b * MWP + wx * MAXN + wy, kx = cx * WIN + cy;
    unsigned posx = S[OFF_WLOCX + binx] + S[OFF_BOFF + (binx >> 10)]
                  + rank_in(S, binx, kx);
    if (posx < (unsigned)n) out[P + (long)n + posx] = (float)i;

    int biny = b * MWP + wy * MAXN + wx, ky = cy * WIN + cx;
    unsigned posy = S[OFF_WLOCY + biny] + S[OFF_BOFF + SCANBLK + (biny >> 10)]
                  + rank_in(S + OFF_BMY, biny, ky);
    if (posy < (unsigned)n) out[P + 2L * n + posy] = (float)i;

    out[P + i] = (float)(i + (i / nper) * gap);   // win2flat
}

// flat2win (chunk 0), coalesced writes, pure closed form
__global__ void k_f2w(float* __restrict__ out, int nper, int nump, int P, int gap) {
    int p = blockIdx.x * blockDim.x + threadIdx.x;
    if (p >= P) return;
    int batch = (p >= nump) + (p >= 2 * nump) + (p >= 3 * nump);
    int off = p - batch * nump;
    int j;
    if (off < nper) j = p - batch * gap;
    else if (nump > GROUP) j = p - GROUP - batch * gap;
    else { int safe = nper > 0 ? nper : 1; j = batch * nper + (off - nper) % safe; }
    out[p] = (float)j;
}

// output-order gather of padded rows. 256 threads = 8 groups of 32 lanes;
// each group owns 8 rows (batched load->store for 8 independent chains).
__global__ void __launch_bounds__(256) k_pad(const float* __restrict__ feats,
                                             float* out,
                                             int nper, int nump, int P, int gap, int n,
                                             long padBase, long permBase) {
    int t = threadIdx.x;
    int rg = t >> 5;          // row group 0..7
    int l = t & 31;           // lane within row
    long base = (long)blockIdx.x * 64 + rg;

    int srcs[8];
#pragma unroll
    for (int u = 0; u < 8; ++u) {
        long p = base + u * 8;
        int pi = (int)p;
        int batch = (pi >= nump) + (pi >= 2 * nump) + (pi >= 3 * nump);
        int off = pi - batch * nump;
        int j;
        if (off < nper) j = pi - batch * gap;
        else if (nump > GROUP) j = pi - GROUP - batch * gap;
        else { int safe = nper > 0 ? nper : 1; j = batch * nper + (off - nper) % safe; }
        int src = (p < P) ? (int)out[permBase + j] : 0;
        if (src < 0) src = 0;
        if (src >= n) src = n - 1;
        srcs[u] = src;
    }
    f32x4 v[8];
#pragma unroll
    for (int u = 0; u < 8; ++u) {
        v[u] = __builtin_nontemporal_load(
            reinterpret_cast<const f32x4*>(feats + (size_t)srcs[u] * CH + l * 4));
    }
#pragma unroll
    for (int u = 0; u < 8; ++u) {
        long p = base + u * 8;
        if (p < P) {
            __builtin_nontemporal_store(v[u],
                reinterpret_cast<f32x4*>(out + padBase + p * CH + l * 4));
        }
    }
}

extern "C" void kernel_launch(void* const* d_in, const int* in_sizes, int n_in,
                              void* d_out, int out_size, void* d_ws, size_t ws_size,
                              hipStream_t stream) {
    const int* coords = (const int*)d_in[0];
    const float* feats = (const float*)d_in[1];
    int n = in_sizes[0] / 3;                              // 999964
    int nper = n / NBATCH;                                // 249991 (equal per batch)
    int nump = (nper + GROUP - 1) / GROUP * GROUP;        // 250112
    int gap  = nump - nper;                               // 121 (bias[b] = b*gap)
    long P   = (long)NBATCH * nump;                       // 1000448 (divisible by 64)
    float* out = (float*)d_out;
    long padBase = P + 3L * n;
    long permBase = P + (long)n;

    // scratch lives at the head of the padded chunk (overwritten last by k_pad)
    unsigned* S = reinterpret_cast<unsigned*>(out + padBase);

    int blocks = (n + 255) / 256;

    (void)hipMemsetAsync(S, 0, (size_t)2 * BMWORDS * sizeof(unsigned), stream);
    k_bits_both<<<blocks, 256, 0, stream>>>(coords, n, S);
    k_scan_local<<<2 * SCANBLK, 1024, 0, stream>>>(S);
    k_scan_top<<<1, 64, 0, stream>>>(S);
    k_finalize<<<blocks, 256, 0, stream>>>(coords, n, S, out, nper, gap, P);
    k_f2w<<<(int)((P + 255) / 256), 256, 0, stream>>>(out, nper, nump, (int)P, gap);
    k_pad<<<(int)((P + 63) / 64), 256, 0, stream>>>(feats, out, nper, nump, (int)P,
                                                    gap, n, padBase, permBase);
}

// Round 13
// 335.989 us; speedup vs baseline: 1.0203x; 1.0203x over previous
//
#include <hip/hip_runtime.h>

#define WIN     12
#define GROUP   128
#define NBATCH  4
#define MAXN    87              // ceil(1024/12)+1 = max_nx = max_ny
#define MWP     (MAXN*MAXN)     // 7569 windows per batch
#define NW      (NBATCH*MWP)    // 30276 batch-major window bins
#define NWORDS  5               // ceil(144/32) bitmap words per window
#define CH      128             // feature channels
#define BMWORDS (NW*NWORDS)     // 151380
#define SCANBLK 30              // ceil(NW/1024) scan blocks per axis

typedef float f32x4 __attribute__((ext_vector_type(4)));

// scratch layout (u32 units) at S = (unsigned*)(out + padBase):
#define OFF_BMY   BMWORDS
#define OFF_WLOCX (2*BMWORDS)
#define OFF_WLOCY (2*BMWORDS + NW)
#define OFF_BSUM  (2*BMWORDS + 2*NW)
#define OFF_BOFF  (2*BMWORDS + 2*NW + 2*SCANBLK)

// one pass over coords: set occupancy bits in BOTH axis bitmaps
__global__ void k_bits_both(const int* __restrict__ coords, int n, unsigned* __restrict__ S) {
    int i = blockIdx.x * blockDim.x + threadIdx.x;
    if (i >= n) return;
    int b = coords[3 * i];
    int y = coords[3 * i + 1];
    int x = coords[3 * i + 2];
    if (b < 0 || b >= NBATCH || x < 0 || y < 0) return;
    int wx = x / WIN, cx = x % WIN;
    int wy = y / WIN, cy = y % WIN;
    int binx = b * MWP + wx * MAXN + wy, kx = cx * WIN + cy;
    int biny = b * MWP + wy * MAXN + wx, ky = cy * WIN + cx;
    atomicOr(&S[binx * NWORDS + (kx >> 5)], 1u << (kx & 31));
    atomicOr(&S[OFF_BMY + biny * NWORDS + (ky >> 5)], 1u << (ky & 31));
}

// per-1024-bin local exclusive scan + block totals, shfl-based (2 barriers).
// blockIdx < SCANBLK -> X axis.
__global__ void k_scan_local(unsigned* __restrict__ S) {
    int axis = blockIdx.x >= SCANBLK;
    int blk = blockIdx.x - axis * SCANBLK;
    const unsigned* bm = S + (axis ? OFF_BMY : 0);
    unsigned* wloc = S + (axis ? OFF_WLOCY : OFF_WLOCX);
    __shared__ unsigned wtot[16], woff[16];
    int t = threadIdx.x;
    int lane = t & 63, wv = t >> 6;
    int w = blk * 1024 + t;
    unsigned cnt = 0;
    if (w < NW) {
#pragma unroll
        for (int k = 0; k < NWORDS; ++k) cnt += __popc(bm[w * NWORDS + k]);
    }
    // wave64 inclusive scan
    unsigned inc = cnt;
#pragma unroll
    for (int off = 1; off < 64; off <<= 1) {
        unsigned v = __shfl_up(inc, off, 64);
        if (lane >= off) inc += v;
    }
    if (lane == 63) wtot[wv] = inc;
    __syncthreads();
    if (wv == 0 && lane < 16) {
        unsigned v = wtot[lane];
        unsigned s = v;
#pragma unroll
        for (int off = 1; off < 16; off <<= 1) {
            unsigned u = __shfl_up(s, off, 64);
            if (lane >= off) s += u;
        }
        woff[lane] = s - v;                 // exclusive wave offset
        if (lane == 15) S[OFF_BSUM + blockIdx.x] = s;  // block total
    }
    __syncthreads();
    if (w < NW) wloc[w] = woff[wv] + inc - cnt;
}

// scan the 2x30 block totals (trivial serial per axis)
__global__ void k_scan_top(unsigned* __restrict__ S) {
    int t = threadIdx.x;
    if (t < 2) {
        unsigned acc = 0;
        for (int k = 0; k < SCANBLK; ++k) {
            S[OFF_BOFF + t * SCANBLK + k] = acc;
            acc += S[OFF_BSUM + t * SCANBLK + k];
        }
    }
}

__device__ __forceinline__ unsigned rank_in(const unsigned* __restrict__ bm, int bin, int k) {
    int wi = k >> 5;
    unsigned bit = (unsigned)(k & 31);
    unsigned r = 0;
    const unsigned* wp = &bm[bin * NWORDS];
#pragma unroll
    for (int w = 0; w < NWORDS; ++w) {
        unsigned m = wp[w];
        if (w < wi) r += __popc(m);
        else if (w == wi) r += __popc(m & ((1u << bit) - 1u));
    }
    return r;
}

// fused: per point perm_x/perm_y (scattered 4B) + win2flat (seq) + flat2win (seq).
// grid covers P (>= n).
__global__ void k_finalize(const int* __restrict__ coords, int n,
                           const unsigned* __restrict__ S,
                           float* __restrict__ out,
                           int nper, int nump, int P, int gap) {
    int i = blockIdx.x * blockDim.x + threadIdx.x;

    if (i < P) {  // flat2win (chunk 0), coalesced
        int batch = (i >= nump) + (i >= 2 * nump) + (i >= 3 * nump);
        int off = i - batch * nump;
        int j;
        if (off < nper) j = i - batch * gap;
        else if (nump > GROUP) j = i - GROUP - batch * gap;
        else { int safe = nper > 0 ? nper : 1; j = batch * nper + (off - nper) % safe; }
        out[i] = (float)j;
    }

    if (i >= n) return;
    long P_ = P;
    int b = coords[3 * i];
    int y = coords[3 * i + 1];
    int x = coords[3 * i + 2];
    if (b < 0 || b >= NBATCH || x < 0 || y < 0) return;
    int wx = x / WIN, cx = x % WIN;
    int wy = y / WIN, cy = y % WIN;

    int binx = b * MWP + wx * MAXN + wy, kx = cx * WIN + cy;
    unsigned posx = S[OFF_WLOCX + binx] + S[OFF_BOFF + (binx >> 10)]
                  + rank_in(S, binx, kx);
    if (posx < (unsigned)n) out[P_ + (long)n + posx] = (float)i;

    int biny = b * MWP + wy * MAXN + wx, ky = cy * WIN + cx;
    unsigned posy = S[OFF_WLOCY + biny] + S[OFF_BOFF + SCANBLK + (biny >> 10)]
                  + rank_in(S + OFF_BMY, biny, ky);
    if (posy < (unsigned)n) out[P_ + 2L * n + posy] = (float)i;

    // win2flat, compare-based batch (equal per-batch counts)
    int fb = (i >= nper) + (i >= 2 * nper) + (i >= 3 * nper);
    out[P_ + i] = (float)(i + fb * gap);
}

// output-order gather of padded rows. 256 threads = 8 groups of 32 lanes;
// each group owns 4 rows (best-measured config, round 11).
__global__ void __launch_bounds__(256) k_pad(const float* __restrict__ feats,
                                             float* out,
                                             int nper, int nump, int P, int gap, int n,
                                             long padBase, long permBase) {
    int t = threadIdx.x;
    int rg = t >> 5;          // row group 0..7
    int l = t & 31;           // lane within row
    long p0 = (long)blockIdx.x * 32 + rg;
#pragma unroll
    for (int u = 0; u < 4; ++u) {
        long p = p0 + u * 8;
        if (p < P) {
            int pi = (int)p;
            int batch = (pi >= nump) + (pi >= 2 * nump) + (pi >= 3 * nump);
            int off = pi - batch * nump;
            int j;
            if (off < nper) j = pi - batch * gap;
            else if (nump > GROUP) j = pi - GROUP - batch * gap;
            else { int safe = nper > 0 ? nper : 1; j = batch * nper + (off - nper) % safe; }
            int src = (int)out[permBase + j];            // perm_x[j] (exact in f32)
            if (src < 0) src = 0;
            if (src >= n) src = n - 1;
            const f32x4 v = __builtin_nontemporal_load(
                reinterpret_cast<const f32x4*>(feats + (size_t)src * CH + l * 4));
            __builtin_nontemporal_store(v,
                reinterpret_cast<f32x4*>(out + padBase + p * CH + l * 4));
        }
    }
}

extern "C" void kernel_launch(void* const* d_in, const int* in_sizes, int n_in,
                              void* d_out, int out_size, void* d_ws, size_t ws_size,
                              hipStream_t stream) {
    const int* coords = (const int*)d_in[0];
    const float* feats = (const float*)d_in[1];
    int n = in_sizes[0] / 3;                              // 999964
    int nper = n / NBATCH;                                // 249991 (equal per batch)
    int nump = (nper + GROUP - 1) / GROUP * GROUP;        // 250112
    int gap  = nump - nper;                               // 121 (bias[b] = b*gap)
    long P   = (long)NBATCH * nump;                       // 1000448 (divisible by 64)
    float* out = (float*)d_out;
    long padBase = P + 3L * n;
    long permBase = P + (long)n;

    // scratch lives at the head of the padded chunk (overwritten last by k_pad)
    unsigned* S = reinterpret_cast<unsigned*>(out + padBase);

    int blocks = (n + 255) / 256;
    int blocksP = (int)((P + 255) / 256);

    (void)hipMemsetAsync(S, 0, (size_t)2 * BMWORDS * sizeof(unsigned), stream);
    k_bits_both<<<blocks, 256, 0, stream>>>(coords, n, S);
    k_scan_local<<<2 * SCANBLK, 1024, 0, stream>>>(S);
    k_scan_top<<<1, 64, 0, stream>>>(S);
    k_finalize<<<blocksP, 256, 0, stream>>>(coords, n, S, out, nper, nump, (int)P, gap);
    k_pad<<<(int)((P + 31) / 32), 256, 0, stream>>>(feats, out, nper, nump, (int)P,
                                                    gap, n, padBase, permBase);
}